// Round 2
// baseline (201.852 us; speedup 1.0000x reference)
//
#include <hip/hip_runtime.h>

// ---------------- problem constants (fixed by reference setup) ----------------
#define B_SAMPLES 8192
#define HIDDEN    512
#define NCLS      10
#define STYLE_D   64
#define LATENT_D  16

#define BM 64
#define BN 64
#define BKT 64                         // K-step per LDS tile
#define MAXT   (B_SAMPLES/BM + NCLS)   // 138 worst-case row tiles for experts
#define MAXROWS (B_SAMPLES + NCLS*BM)  // 8832 padded sorted rows

typedef short v8s __attribute__((ext_vector_type(8)));
typedef float v4f __attribute__((ext_vector_type(4)));
typedef int   v4i __attribute__((ext_vector_type(4)));

__device__ __forceinline__ short f2bf(float f) {
    union { float f; unsigned u; } x; x.f = f;
    unsigned r = x.u + 0x7fffu + ((x.u >> 16) & 1u);   // RNE; inputs finite
    return (short)(r >> 16);
}

// ---------------- tiny prep kernels ----------------
__global__ void zero_counts(int* counts, int* cursor) {
    if (threadIdx.x < NCLS) { counts[threadIdx.x] = 0; cursor[threadIdx.x] = 0; }
}

__global__ void hist_kernel(const int* __restrict__ y, int* __restrict__ counts) {
    int b = blockIdx.x * 256 + threadIdx.x;
    if (b < B_SAMPLES) atomicAdd(&counts[y[b]], 1);
}

// single block: prefix over 10 classes, build tile->class map, fill order with -1
__global__ void prefix_tiles(const int* __restrict__ counts, int* __restrict__ pstart,
                             int* __restrict__ tclass, int* __restrict__ trow0,
                             int* __restrict__ order) {
    if (threadIdx.x == 0) {
        int off = 0, tt = 0;
        for (int c = 0; c < NCLS; ++c) {
            pstart[c] = off;
            int nt = (counts[c] + BM - 1) / BM;
            for (int j = 0; j < nt; ++j) { tclass[tt] = c; trow0[tt] = off + j * BM; ++tt; }
            off += nt * BM;
        }
        for (int t = tt; t < MAXT; ++t) { tclass[t] = -1; trow0[t] = 0; }
    }
    __syncthreads();
    for (int i = threadIdx.x; i < MAXROWS; i += 256) order[i] = -1;
}

__global__ void scatter_order(const int* __restrict__ y, int* __restrict__ order,
                              const int* __restrict__ pstart, int* __restrict__ cursor) {
    int b = blockIdx.x * 256 + threadIdx.x;
    if (b < B_SAMPLES) {
        int c = y[b];
        int r = atomicAdd(&cursor[c], 1);
        order[pstart[c] + r] = b;
    }
}

// z [8192][16] f32 -> zb [8192][64] bf16, zero-padded k>=16
__global__ void make_zb(const float* __restrict__ z, short* __restrict__ zb) {
    int idx = blockIdx.x * 256 + threadIdx.x;       // 8192*64
    int b = idx >> 6, k = idx & 63;
    zb[idx] = f2bf(k < LATENT_D ? z[b * LATENT_D + k] : 0.f);
}

// sw0 [16][512] f32 -> wt0 [512][64] bf16 (transposed, zero-padded k>=16)
__global__ void make_wt0(const float* __restrict__ sw0, short* __restrict__ wt0) {
    int idx = blockIdx.x * 256 + threadIdx.x;       // 512*64
    int n = idx >> 6, k = idx & 63;
    wt0[idx] = f2bf(k < LATENT_D ? sw0[k * HIDDEN + n] : 0.f);
}

// generic batched transpose: src [K][N] f32 (batch stride K*N) -> dst [N][K] bf16
__global__ void transpose_w(const float* __restrict__ src, short* __restrict__ dst,
                            int K, int N) {
    __shared__ float tile[32][33];
    const float* s = src + (size_t)blockIdx.z * K * N;
    short*       d = dst + (size_t)blockIdx.z * K * N;
    int n0 = blockIdx.x * 32, k0 = blockIdx.y * 32;
    int tx = threadIdx.x, ty = threadIdx.y;         // 32 x 8
    #pragma unroll
    for (int j = 0; j < 32; j += 8)
        tile[ty + j][tx] = s[(size_t)(k0 + ty + j) * N + n0 + tx];
    __syncthreads();
    #pragma unroll
    for (int j = 0; j < 32; j += 8)
        d[(size_t)(n0 + ty + j) * K + k0 + tx] = f2bf(tile[tx][ty + j]);
}

// ---------------- core GEMM ----------------
// Out[m][n] = act( A[m][:] . WT[n][:] + bias[n] )
// MODE 0: trunk   (rows direct, relu, bf16 out)
// MODE 1: expert first (rows gathered via order[], relu, bf16 out)
// MODE 2: expert mid   (rows sorted-linear, relu, bf16 out)
// MODE 3: expert last  (rows sorted-linear, no relu, scatter FP32 rows to d_out)
template <int MODE>
__global__ __launch_bounds__(256) void gemm64(
    const short* __restrict__ A, const short* __restrict__ WT,
    const float* __restrict__ bias, void* __restrict__ Outv,
    int N, int K,
    const int* __restrict__ order, const int* __restrict__ tclass,
    const int* __restrict__ trow0) {

    int tile = blockIdx.y;
    int cls = 0, row0;
    if (MODE == 0) {
        row0 = tile * BM;
    } else {
        cls = tclass[tile];
        if (cls < 0) return;            // uniform: whole block exits
        row0 = trow0[tile];
    }
    int n0 = blockIdx.x * BN;
    const short* wt = WT + (size_t)cls * N * K;
    const float* bs = bias + (size_t)cls * N;

    __shared__ short As[BM * BKT];
    __shared__ short Bs[BN * BKT];

    int t = threadIdx.x;
    int lane = t & 63, w = t >> 6;
    int wr = w >> 1, wc = w & 1;
    int lrow = lane & 15, lko = lane >> 4;

    v4f acc[2][2] = {};

    for (int k0 = 0; k0 < K; k0 += BKT) {
        // ---- stage A and B tiles (reg-staged, XOR-swizzled LDS writes) ----
        #pragma unroll
        for (int p = 0; p < 2; ++p) {
            int lin = p * 256 + t;
            int row = lin >> 3, c = lin & 7;          // 8 x 16B chunks per 64-elem row
            int swz = (c ^ (row & 7)) << 3;

            v4i va = {0, 0, 0, 0};
            if (MODE == 1) {
                int o = order[row0 + row];
                if (o >= 0) va = *(const v4i*)(A + (size_t)o * K + k0 + c * 8);
            } else {
                va = *(const v4i*)(A + (size_t)(row0 + row) * K + k0 + c * 8);
            }
            *(v4i*)&As[row * BKT + swz] = va;

            v4i vb = *(const v4i*)(wt + (size_t)(n0 + row) * K + k0 + c * 8);
            *(v4i*)&Bs[row * BKT + swz] = vb;
        }
        __syncthreads();

        // ---- fragments + MFMA ----
        v8s af[2][2], bf[2][2];
        #pragma unroll
        for (int kk = 0; kk < 2; ++kk) {
            #pragma unroll
            for (int f = 0; f < 2; ++f) {
                int r = wr * 32 + f * 16 + lrow;
                af[f][kk] = *(const v8s*)&As[r * BKT + (((kk * 4 + lko) ^ (r & 7)) << 3)];
                int n = wc * 32 + f * 16 + lrow;
                bf[f][kk] = *(const v8s*)&Bs[n * BKT + (((kk * 4 + lko) ^ (n & 7)) << 3)];
            }
        }
        #pragma unroll
        for (int kk = 0; kk < 2; ++kk)
            #pragma unroll
            for (int i = 0; i < 2; ++i)
                #pragma unroll
                for (int j = 0; j < 2; ++j)
                    acc[i][j] = __builtin_amdgcn_mfma_f32_16x16x32_bf16(
                        af[i][kk], bf[j][kk], acc[i][j], 0, 0, 0);
        __syncthreads();
    }

    // ---- epilogue: bias (+relu); bf16 store for MODE<3, fp32 scatter for MODE 3 ----
    #pragma unroll
    for (int i = 0; i < 2; ++i)
        #pragma unroll
        for (int j = 0; j < 2; ++j)
            #pragma unroll
            for (int q = 0; q < 4; ++q) {
                int r = wr * 32 + i * 16 + (lane >> 4) * 4 + q;   // C/D: row=(l>>4)*4+reg
                int c = wc * 32 + j * 16 + (lane & 15);           //      col=l&15
                float v = acc[i][j][q] + bs[n0 + c];
                if (MODE != 3) {
                    v = fmaxf(v, 0.f);
                    ((short*)Outv)[(size_t)(row0 + r) * N + n0 + c] = f2bf(v);
                } else {
                    int o = order[row0 + r];
                    if (o >= 0) ((float*)Outv)[(size_t)o * N + n0 + c] = v;
                }
            }
}

// ---------------- launcher ----------------
extern "C" void kernel_launch(void* const* d_in, const int* in_sizes, int n_in,
                              void* d_out, int out_size, void* d_ws, size_t ws_size,
                              hipStream_t stream) {
    const float* z   = (const float*)d_in[0];
    const int*   y   = (const int*)d_in[1];
    const float* sw0 = (const float*)d_in[2];
    const float* sb0 = (const float*)d_in[3];
    const float* sw1 = (const float*)d_in[4];
    const float* sb1 = (const float*)d_in[5];
    const float* sw2 = (const float*)d_in[6];
    const float* sb2 = (const float*)d_in[7];
    const float* sw3 = (const float*)d_in[8];
    const float* sb3 = (const float*)d_in[9];
    const float* uw0 = (const float*)d_in[10];
    const float* ub0 = (const float*)d_in[11];
    const float* uw1 = (const float*)d_in[12];
    const float* ub1 = (const float*)d_in[13];
    const float* uw2 = (const float*)d_in[14];
    const float* ub2 = (const float*)d_in[15];
    const float* uw3 = (const float*)d_in[16];
    const float* ub3 = (const float*)d_in[17];

    char* p = (char*)d_ws;
    auto alloc = [&](size_t bytes) -> char* {
        char* r = p; p += (bytes + 255) & ~(size_t)255; return r;
    };
    int*   counts = (int*)alloc(NCLS * 4);
    int*   cursor = (int*)alloc(NCLS * 4);
    int*   pstart = (int*)alloc(NCLS * 4);
    int*   tclass = (int*)alloc(MAXT * 4);
    int*   trow0  = (int*)alloc(MAXT * 4);
    int*   order  = (int*)alloc(MAXROWS * 4);
    short* zb     = (short*)alloc((size_t)B_SAMPLES * 64 * 2);
    short* wt0    = (short*)alloc((size_t)HIDDEN * 64 * 2);
    short* wt1    = (short*)alloc((size_t)HIDDEN * HIDDEN * 2);
    short* wt2    = (short*)alloc((size_t)HIDDEN * HIDDEN * 2);
    short* wt3    = (short*)alloc((size_t)HIDDEN * HIDDEN * 2);
    short* wtu0   = (short*)alloc((size_t)NCLS * HIDDEN * HIDDEN * 2);
    short* wtu1   = (short*)alloc((size_t)NCLS * HIDDEN * HIDDEN * 2);
    short* wtu2   = (short*)alloc((size_t)NCLS * HIDDEN * HIDDEN * 2);
    short* wtu3   = (short*)alloc((size_t)NCLS * STYLE_D * HIDDEN * 2);
    short* act0   = (short*)alloc((size_t)MAXROWS * HIDDEN * 2);
    short* act1   = (short*)alloc((size_t)MAXROWS * HIDDEN * 2);

    // ---- class grouping ----
    zero_counts<<<1, 64, 0, stream>>>(counts, cursor);
    hist_kernel<<<B_SAMPLES / 256, 256, 0, stream>>>(y, counts);
    prefix_tiles<<<1, 256, 0, stream>>>(counts, pstart, tclass, trow0, order);
    scatter_order<<<B_SAMPLES / 256, 256, 0, stream>>>(y, order, pstart, cursor);

    // ---- weight prep (bf16, transposed) ----
    make_zb<<<(B_SAMPLES * 64) / 256, 256, 0, stream>>>(z, zb);
    make_wt0<<<(HIDDEN * 64) / 256, 256, 0, stream>>>(sw0, wt0);
    dim3 tb(32, 8);
    transpose_w<<<dim3(16, 16, 1), tb, 0, stream>>>(sw1, wt1, HIDDEN, HIDDEN);
    transpose_w<<<dim3(16, 16, 1), tb, 0, stream>>>(sw2, wt2, HIDDEN, HIDDEN);
    transpose_w<<<dim3(16, 16, 1), tb, 0, stream>>>(sw3, wt3, HIDDEN, HIDDEN);
    transpose_w<<<dim3(16, 16, NCLS), tb, 0, stream>>>(uw0, wtu0, HIDDEN, HIDDEN);
    transpose_w<<<dim3(16, 16, NCLS), tb, 0, stream>>>(uw1, wtu1, HIDDEN, HIDDEN);
    transpose_w<<<dim3(16, 16, NCLS), tb, 0, stream>>>(uw2, wtu2, HIDDEN, HIDDEN);
    transpose_w<<<dim3(2, 16, NCLS), tb, 0, stream>>>(uw3, wtu3, HIDDEN, STYLE_D);

    // ---- trunk: 4 x (Linear + ReLU) ----
    gemm64<0><<<dim3(HIDDEN / BN, B_SAMPLES / BM), 256, 0, stream>>>(
        zb, wt0, sb0, act0, HIDDEN, 64, nullptr, nullptr, nullptr);
    gemm64<0><<<dim3(HIDDEN / BN, B_SAMPLES / BM), 256, 0, stream>>>(
        act0, wt1, sb1, act1, HIDDEN, HIDDEN, nullptr, nullptr, nullptr);
    gemm64<0><<<dim3(HIDDEN / BN, B_SAMPLES / BM), 256, 0, stream>>>(
        act1, wt2, sb2, act0, HIDDEN, HIDDEN, nullptr, nullptr, nullptr);
    gemm64<0><<<dim3(HIDDEN / BN, B_SAMPLES / BM), 256, 0, stream>>>(
        act0, wt3, sb3, act1, HIDDEN, HIDDEN, nullptr, nullptr, nullptr);

    // ---- selected experts (class-grouped) ----
    gemm64<1><<<dim3(HIDDEN / BN, MAXT), 256, 0, stream>>>(
        act1, wtu0, ub0, act0, HIDDEN, HIDDEN, order, tclass, trow0);
    gemm64<2><<<dim3(HIDDEN / BN, MAXT), 256, 0, stream>>>(
        act0, wtu1, ub1, act1, HIDDEN, HIDDEN, order, tclass, trow0);
    gemm64<2><<<dim3(HIDDEN / BN, MAXT), 256, 0, stream>>>(
        act1, wtu2, ub2, act0, HIDDEN, HIDDEN, order, tclass, trow0);
    gemm64<3><<<dim3(1, MAXT), 256, 0, stream>>>(
        act0, wtu3, ub3, d_out, STYLE_D, HIDDEN, order, tclass, trow0);
}

// Round 3
// 160.133 us; speedup vs baseline: 1.2605x; 1.2605x over previous
//
#include <hip/hip_runtime.h>

// ---------------- problem constants ----------------
#define B_SAMPLES 8192
#define HIDDEN    512
#define NCLS      10
#define STYLE_D   64
#define LATENT_D  16

#define BM 128
#define BN 128
#define BK 64
#define MAXT    (B_SAMPLES/BM + NCLS)     // 74 worst-case expert row tiles
#define MAXROWS (B_SAMPLES + NCLS*BM)     // 9472 padded sorted rows

typedef short v8s __attribute__((ext_vector_type(8)));
typedef float v4f __attribute__((ext_vector_type(4)));

__device__ __forceinline__ short f2bf(float f) {
    union { float f; unsigned u; } x; x.f = f;
    unsigned r = x.u + 0x7fffu + ((x.u >> 16) & 1u);   // RNE; inputs finite
    return (short)(r >> 16);
}

__device__ __forceinline__ void gload16(const short* g, short* l) {
    __builtin_amdgcn_global_load_lds(
        (const __attribute__((address_space(1))) void*)g,
        (__attribute__((address_space(3))) void*)l, 16, 0, 0);
}

// ---------------- fused grouping (one block) ----------------
// counts -> padded-to-128 class segments -> tile maps + order (pos->sample)
// + rank (sample->pos). Padding slots keep order = -1.
__global__ void build_groups(const int* __restrict__ y, int* __restrict__ tclass,
                             int* __restrict__ trow0, int* __restrict__ order,
                             int* __restrict__ rank) {
    __shared__ int cnt[NCLS], cur[NCLS];
    int t = threadIdx.x;                       // 1024 threads
    if (t < NCLS) cnt[t] = 0;
    __syncthreads();
    for (int b = t; b < B_SAMPLES; b += 1024) atomicAdd(&cnt[y[b]], 1);
    __syncthreads();
    if (t == 0) {
        int off = 0, tt = 0;
        for (int c = 0; c < NCLS; ++c) {
            cur[c] = off;
            int nt = (cnt[c] + BM - 1) / BM;
            for (int j = 0; j < nt; ++j) { tclass[tt] = c; trow0[tt] = off + j * BM; ++tt; }
            off += nt * BM;
        }
        for (int u = tt; u < MAXT; ++u) { tclass[u] = -1; trow0[u] = 0; }
    }
    __syncthreads();
    for (int i = t; i < MAXROWS; i += 1024) order[i] = -1;
    __syncthreads();
    for (int b = t; b < B_SAMPLES; b += 1024) {
        int c = y[b];
        int p = atomicAdd(&cur[c], 1);
        order[p] = b;
        rank[b] = p;
    }
}

// ---------------- weight/input prep ----------------
// zb [8192][64] bf16 (K-padded z) and wt0 [512][64] bf16 (transposed, K-padded)
__global__ void prep_zb_wt0(const float* __restrict__ z, const float* __restrict__ sw0,
                            short* __restrict__ zb, short* __restrict__ wt0) {
    int idx = blockIdx.x * 256 + threadIdx.x;
    if (idx < B_SAMPLES * 64) {
        int b = idx >> 6, k = idx & 63;
        zb[idx] = f2bf(k < LATENT_D ? z[b * LATENT_D + k] : 0.f);
    } else {
        int i = idx - B_SAMPLES * 64;          // 512*64
        int n = i >> 6, k = i & 63;
        wt0[i] = f2bf(k < LATENT_D ? sw0[(size_t)k * HIDDEN + n] : 0.f);
    }
}

// 33 slices of 512x512 f32 -> bf16 transposed: sw1,sw2,sw3, uw0[10], uw1[10], uw2[10]
__global__ void transpose_all(const float* __restrict__ sw1, const float* __restrict__ sw2,
                              const float* __restrict__ sw3, const float* __restrict__ uw0,
                              const float* __restrict__ uw1, const float* __restrict__ uw2,
                              short* __restrict__ wt1, short* __restrict__ wt2,
                              short* __restrict__ wt3, short* __restrict__ wtu0,
                              short* __restrict__ wtu1, short* __restrict__ wtu2) {
    __shared__ float tile[32][33];
    int zz = blockIdx.z;
    const float* s; short* d;
    if      (zz == 0) { s = sw1; d = wt1; }
    else if (zz == 1) { s = sw2; d = wt2; }
    else if (zz == 2) { s = sw3; d = wt3; }
    else if (zz < 13) { size_t o = (size_t)(zz - 3)  * HIDDEN * HIDDEN; s = uw0 + o; d = wtu0 + o; }
    else if (zz < 23) { size_t o = (size_t)(zz - 13) * HIDDEN * HIDDEN; s = uw1 + o; d = wtu1 + o; }
    else              { size_t o = (size_t)(zz - 23) * HIDDEN * HIDDEN; s = uw2 + o; d = wtu2 + o; }
    int n0 = blockIdx.x * 32, k0 = blockIdx.y * 32;
    int tx = threadIdx.x, ty = threadIdx.y;    // 32 x 8
    #pragma unroll
    for (int j = 0; j < 32; j += 8)
        tile[ty + j][tx] = s[(size_t)(k0 + ty + j) * HIDDEN + n0 + tx];
    __syncthreads();
    #pragma unroll
    for (int j = 0; j < 32; j += 8)
        d[(size_t)(n0 + ty + j) * HIDDEN + k0 + tx] = f2bf(tile[tx][ty + j]);
}

// uw3 [10][512][64] -> wtu3 [10][128][512] bf16 (rows 0..63 valid; 64..127 unused)
__global__ void make_wtu3(const float* __restrict__ uw3, short* __restrict__ wtu3) {
    __shared__ float tile[32][33];
    int cls = blockIdx.z;
    const float* s = uw3  + (size_t)cls * HIDDEN * STYLE_D;
    short*       d = wtu3 + (size_t)cls * BN * HIDDEN;
    int n0 = blockIdx.x * 32, k0 = blockIdx.y * 32;
    int tx = threadIdx.x, ty = threadIdx.y;
    #pragma unroll
    for (int j = 0; j < 32; j += 8)
        tile[ty + j][tx] = s[(size_t)(k0 + ty + j) * STYLE_D + n0 + tx];
    __syncthreads();
    #pragma unroll
    for (int j = 0; j < 32; j += 8)
        d[(size_t)(n0 + ty + j) * HIDDEN + k0 + tx] = f2bf(tile[tx][ty + j]);
}

// ---------------- core GEMM: m97 structure ----------------
// 128x128 tile, BK=64, 4 waves (2x2), 4x4 16x16x32 frags/wave,
// linear LDS + global_load_lds(16) staging.
// MODE 0: trunk, linear rows, relu, bf16 out
// MODE 1: trunk L3, relu, bf16 out scattered to rank[row]
// MODE 2: expert mid, tile rows, relu, bf16 out
// MODE 3: expert last, tile rows, no relu, fp32 scatter to d_out via order[]
template <int MODE>
__global__ __launch_bounds__(256) void gemm128(
    const short* __restrict__ A, const short* __restrict__ WT,
    const float* __restrict__ bias, void* __restrict__ Outv,
    const int N, const int K, const long wStride, const int biasN,
    const int* __restrict__ aux, const int* __restrict__ tclass,
    const int* __restrict__ trow0) {

    int tile = blockIdx.y, cls = 0, row0;
    if (MODE <= 1) {
        row0 = tile * BM;
    } else {
        cls = tclass[tile];
        if (cls < 0) return;               // uniform block exit
        row0 = trow0[tile];
    }
    const int n0 = blockIdx.x * BN;
    const short* wt = WT + (size_t)cls * wStride;
    const float* bs = bias + (size_t)cls * biasN;

    __shared__ short As[BM * BK];
    __shared__ short Bs[BN * BK];

    const int t = threadIdx.x, lane = t & 63, w = t >> 6;
    const int srow = lane >> 3, scol = (lane & 7) * 8;   // 8 lanes x 16B per row
    const int wr = w >> 1, wc = w & 1;
    const int lrow = lane & 15, lko = lane >> 4;

    v4f acc[4][4] = {};

    for (int k0 = 0; k0 < K; k0 += BK) {
        #pragma unroll
        for (int p = 0; p < 4; ++p) {
            int row = p * 32 + w * 8 + srow;
            gload16(A  + (size_t)(row0 + row) * K + k0 + scol, &As[(p * 256 + w * 64) * 8]);
            gload16(wt + (size_t)(n0  + row) * K + k0 + scol, &Bs[(p * 256 + w * 64) * 8]);
        }
        __syncthreads();

        #pragma unroll
        for (int kk = 0; kk < 2; ++kk) {
            v8s af[4], bq[4];
            #pragma unroll
            for (int i = 0; i < 4; ++i)
                af[i] = *(const v8s*)&As[(wr * 64 + i * 16 + lrow) * BK + kk * 32 + lko * 8];
            #pragma unroll
            for (int j = 0; j < 4; ++j)
                bq[j] = *(const v8s*)&Bs[(wc * 64 + j * 16 + lrow) * BK + kk * 32 + lko * 8];
            #pragma unroll
            for (int i = 0; i < 4; ++i)
                #pragma unroll
                for (int j = 0; j < 4; ++j)
                    acc[i][j] = __builtin_amdgcn_mfma_f32_16x16x32_bf16(
                        af[i], bq[j], acc[i][j], 0, 0, 0);
        }
        __syncthreads();
    }

    // ---- epilogue ----
    #pragma unroll
    for (int i = 0; i < 4; ++i)
        #pragma unroll
        for (int j = 0; j < 4; ++j)
            #pragma unroll
            for (int q = 0; q < 4; ++q) {
                int r = wr * 64 + i * 16 + lko * 4 + q;   // C/D: row=(l>>4)*4+reg
                int c = wc * 64 + j * 16 + lrow;          //      col=l&15
                if (MODE == 3) {
                    int cc = n0 + c;
                    if (cc < STYLE_D) {
                        int o = aux[row0 + r];            // order (pos -> sample)
                        if (o >= 0)
                            ((float*)Outv)[(size_t)o * STYLE_D + cc] = acc[i][j][q] + bs[cc];
                    }
                } else {
                    float v = fmaxf(acc[i][j][q] + bs[n0 + c], 0.f);
                    size_t orow = (MODE == 1) ? (size_t)aux[row0 + r]   // rank (sample -> pos)
                                              : (size_t)(row0 + r);
                    ((short*)Outv)[orow * N + n0 + c] = f2bf(v);
                }
            }
}

// ---------------- launcher ----------------
extern "C" void kernel_launch(void* const* d_in, const int* in_sizes, int n_in,
                              void* d_out, int out_size, void* d_ws, size_t ws_size,
                              hipStream_t stream) {
    const float* z   = (const float*)d_in[0];
    const int*   y   = (const int*)d_in[1];
    const float* sw0 = (const float*)d_in[2];
    const float* sb0 = (const float*)d_in[3];
    const float* sw1 = (const float*)d_in[4];
    const float* sb1 = (const float*)d_in[5];
    const float* sw2 = (const float*)d_in[6];
    const float* sb2 = (const float*)d_in[7];
    const float* sw3 = (const float*)d_in[8];
    const float* sb3 = (const float*)d_in[9];
    const float* uw0 = (const float*)d_in[10];
    const float* ub0 = (const float*)d_in[11];
    const float* uw1 = (const float*)d_in[12];
    const float* ub1 = (const float*)d_in[13];
    const float* uw2 = (const float*)d_in[14];
    const float* ub2 = (const float*)d_in[15];
    const float* uw3 = (const float*)d_in[16];
    const float* ub3 = (const float*)d_in[17];

    char* p = (char*)d_ws;
    auto alloc = [&](size_t bytes) -> char* {
        char* r = p; p += (bytes + 255) & ~(size_t)255; return r;
    };
    int*   tclass = (int*)alloc(MAXT * 4);
    int*   trow0  = (int*)alloc(MAXT * 4);
    int*   order  = (int*)alloc(MAXROWS * 4);
    int*   rank   = (int*)alloc(B_SAMPLES * 4);
    short* zb     = (short*)alloc((size_t)B_SAMPLES * 64 * 2);
    short* wt0    = (short*)alloc((size_t)HIDDEN * 64 * 2);
    short* wt1    = (short*)alloc((size_t)HIDDEN * HIDDEN * 2);
    short* wt2    = (short*)alloc((size_t)HIDDEN * HIDDEN * 2);
    short* wt3    = (short*)alloc((size_t)HIDDEN * HIDDEN * 2);
    short* wtu0   = (short*)alloc((size_t)NCLS * HIDDEN * HIDDEN * 2);
    short* wtu1   = (short*)alloc((size_t)NCLS * HIDDEN * HIDDEN * 2);
    short* wtu2   = (short*)alloc((size_t)NCLS * HIDDEN * HIDDEN * 2);
    short* wtu3   = (short*)alloc((size_t)NCLS * BN * HIDDEN * 2);   // N-padded to 128
    short* act0   = (short*)alloc((size_t)MAXROWS * HIDDEN * 2);
    short* act1   = (short*)alloc((size_t)MAXROWS * HIDDEN * 2);
    short* act2   = (short*)alloc((size_t)MAXROWS * HIDDEN * 2);     // sorted trunk out

    // grouping + zero the sorted buffer (padding rows must read as 0)
    build_groups<<<1, 1024, 0, stream>>>(y, tclass, trow0, order, rank);
    hipMemsetAsync(act2, 0, (size_t)MAXROWS * HIDDEN * 2, stream);

    // weight prep
    prep_zb_wt0<<<(B_SAMPLES * 64 + HIDDEN * 64) / 256, 256, 0, stream>>>(z, sw0, zb, wt0);
    dim3 tb(32, 8);
    transpose_all<<<dim3(16, 16, 33), tb, 0, stream>>>(sw1, sw2, sw3, uw0, uw1, uw2,
                                                       wt1, wt2, wt3, wtu0, wtu1, wtu2);
    make_wtu3<<<dim3(2, 16, NCLS), tb, 0, stream>>>(uw3, wtu3);

    // trunk
    gemm128<0><<<dim3(HIDDEN / BN, B_SAMPLES / BM), 256, 0, stream>>>(
        zb, wt0, sb0, act0, HIDDEN, 64, 0, 0, nullptr, nullptr, nullptr);
    gemm128<0><<<dim3(HIDDEN / BN, B_SAMPLES / BM), 256, 0, stream>>>(
        act0, wt1, sb1, act1, HIDDEN, HIDDEN, 0, 0, nullptr, nullptr, nullptr);
    gemm128<0><<<dim3(HIDDEN / BN, B_SAMPLES / BM), 256, 0, stream>>>(
        act1, wt2, sb2, act0, HIDDEN, HIDDEN, 0, 0, nullptr, nullptr, nullptr);
    gemm128<1><<<dim3(HIDDEN / BN, B_SAMPLES / BM), 256, 0, stream>>>(
        act0, wt3, sb3, act2, HIDDEN, HIDDEN, 0, 0, rank, nullptr, nullptr);

    // selected experts (class-grouped, sorted-linear rows)
    gemm128<2><<<dim3(HIDDEN / BN, MAXT), 256, 0, stream>>>(
        act2, wtu0, ub0, act0, HIDDEN, HIDDEN, (long)HIDDEN * HIDDEN, HIDDEN,
        nullptr, tclass, trow0);
    gemm128<2><<<dim3(HIDDEN / BN, MAXT), 256, 0, stream>>>(
        act0, wtu1, ub1, act1, HIDDEN, HIDDEN, (long)HIDDEN * HIDDEN, HIDDEN,
        nullptr, tclass, trow0);
    gemm128<2><<<dim3(HIDDEN / BN, MAXT), 256, 0, stream>>>(
        act1, wtu2, ub2, act0, HIDDEN, HIDDEN, (long)HIDDEN * HIDDEN, HIDDEN,
        nullptr, tclass, trow0);
    gemm128<3><<<dim3(1, MAXT), 256, 0, stream>>>(
        act0, wtu3, ub3, d_out, HIDDEN, HIDDEN, (long)BN * HIDDEN, STYLE_D,
        order, tclass, trow0);
}

// Round 5
// 146.409 us; speedup vs baseline: 1.3787x; 1.0937x over previous
//
#include <hip/hip_runtime.h>

// ---------------- problem constants ----------------
#define B_SAMPLES 8192
#define HIDDEN    512
#define NCLS      10
#define STYLE_D   64
#define LATENT_D  16

#define BM 128
#define BN 64
#define BK 64
#define MAXT    (B_SAMPLES/BM + NCLS)     // 74 worst-case expert row tiles (BM=128 pad)
#define MAXROWS (B_SAMPLES + NCLS*BM)     // 9472 padded sorted rows

typedef short v8s __attribute__((ext_vector_type(8)));
typedef float v4f __attribute__((ext_vector_type(4)));

__device__ __forceinline__ short f2bf(float f) {
    union { float f; unsigned u; } x; x.f = f;
    unsigned r = x.u + 0x7fffu + ((x.u >> 16) & 1u);   // RNE; inputs finite
    return (short)(r >> 16);
}

__device__ __forceinline__ void gload16(const short* g, short* l) {
    __builtin_amdgcn_global_load_lds(
        (const __attribute__((address_space(1))) void*)g,
        (__attribute__((address_space(3))) void*)l, 16, 0, 0);
}

// ---------------- fused grouping (one block) ----------------
// order (pos->sample, -1 in padding), rank (sample->pos), tile->class maps.
__global__ void build_groups(const int* __restrict__ y, int* __restrict__ tclass,
                             int* __restrict__ trow0, int* __restrict__ order,
                             int* __restrict__ rank) {
    __shared__ int cnt[NCLS], cur[NCLS];
    int t = threadIdx.x;                       // 1024 threads
    if (t < NCLS) cnt[t] = 0;
    __syncthreads();
    for (int b = t; b < B_SAMPLES; b += 1024) atomicAdd(&cnt[y[b]], 1);
    __syncthreads();
    if (t == 0) {
        int off = 0, tt = 0;
        for (int c = 0; c < NCLS; ++c) {
            cur[c] = off;
            int nt = (cnt[c] + BM - 1) / BM;
            for (int j = 0; j < nt; ++j) { tclass[tt] = c; trow0[tt] = off + j * BM; ++tt; }
            off += nt * BM;
        }
        for (int u = tt; u < MAXT; ++u) { tclass[u] = -1; trow0[u] = 0; }
    }
    __syncthreads();
    for (int i = t; i < MAXROWS; i += 1024) order[i] = -1;
    __syncthreads();
    for (int b = t; b < B_SAMPLES; b += 1024) {
        int c = y[b];
        int p = atomicAdd(&cur[c], 1);
        order[p] = b;
        rank[b] = p;
    }
}

// ---------------- input prep ----------------
// zb [8192][64] bf16 (K-padded z) and wt0 [512][64] bf16 (transposed, K-padded)
__global__ void prep_zb_wt0(const float* __restrict__ z, const float* __restrict__ sw0,
                            short* __restrict__ zb, short* __restrict__ wt0) {
    int idx = blockIdx.x * 256 + threadIdx.x;
    if (idx < B_SAMPLES * 64) {
        int b = idx >> 6, k = idx & 63;
        zb[idx] = f2bf(k < LATENT_D ? z[b * LATENT_D + k] : 0.f);
    } else {
        int i = idx - B_SAMPLES * 64;          // 512*64
        int n = i >> 6, k = i & 63;
        wt0[i] = f2bf(k < LATENT_D ? sw0[(size_t)k * HIDDEN + n] : 0.f);
    }
}

// mega transpose. grid x = 20.
// z<33 (bx<16 only): 512x512 slices (sw1,sw2,sw3,uw0[10],uw1[10],uw2[10])
// z==33 (bx<20): uw3, cls = bx>>1 (10 classes), n0 = (bx&1)*32
__global__ void transpose_mega(const float* __restrict__ sw1, const float* __restrict__ sw2,
                               const float* __restrict__ sw3, const float* __restrict__ uw0,
                               const float* __restrict__ uw1, const float* __restrict__ uw2,
                               const float* __restrict__ uw3,
                               short* __restrict__ wt1, short* __restrict__ wt2,
                               short* __restrict__ wt3, short* __restrict__ wtu0,
                               short* __restrict__ wtu1, short* __restrict__ wtu2,
                               short* __restrict__ wtu3) {
    __shared__ float tile[32][33];
    int zz = blockIdx.z;
    int tx = threadIdx.x, ty = threadIdx.y;    // 32 x 8
    if (zz == 33) {
        int cls = blockIdx.x >> 1;             // 0..9
        int n0 = (blockIdx.x & 1) * 32, k0 = blockIdx.y * 32;
        const float* s = uw3  + (size_t)cls * HIDDEN * STYLE_D;
        short*       d = wtu3 + (size_t)cls * STYLE_D * HIDDEN;
        #pragma unroll
        for (int j = 0; j < 32; j += 8)
            tile[ty + j][tx] = s[(size_t)(k0 + ty + j) * STYLE_D + n0 + tx];
        __syncthreads();
        #pragma unroll
        for (int j = 0; j < 32; j += 8)
            d[(size_t)(n0 + ty + j) * HIDDEN + k0 + tx] = f2bf(tile[tx][ty + j]);
        return;
    }
    if (blockIdx.x >= 16) return;              // 512x512 slices use 16 x-blocks
    const float* s; short* d;
    if      (zz == 0) { s = sw1; d = wt1; }
    else if (zz == 1) { s = sw2; d = wt2; }
    else if (zz == 2) { s = sw3; d = wt3; }
    else if (zz < 13) { size_t o = (size_t)(zz - 3)  * HIDDEN * HIDDEN; s = uw0 + o; d = wtu0 + o; }
    else if (zz < 23) { size_t o = (size_t)(zz - 13) * HIDDEN * HIDDEN; s = uw1 + o; d = wtu1 + o; }
    else              { size_t o = (size_t)(zz - 23) * HIDDEN * HIDDEN; s = uw2 + o; d = wtu2 + o; }
    int n0 = blockIdx.x * 32, k0 = blockIdx.y * 32;
    #pragma unroll
    for (int j = 0; j < 32; j += 8)
        tile[ty + j][tx] = s[(size_t)(k0 + ty + j) * HIDDEN + n0 + tx];
    __syncthreads();
    #pragma unroll
    for (int j = 0; j < 32; j += 8)
        d[(size_t)(n0 + ty + j) * HIDDEN + k0 + tx] = f2bf(tile[tx][ty + j]);
}

// ---------------- core GEMM: 128x64 tile, BK=64, 4 waves (2x2), 4x2 frags ----
// MODE 0: trunk, linear rows, relu, bf16 out
// MODE 1: trunk L3, relu, bf16 out scattered to rank[row]
// MODE 2: expert mid, tile rows, relu, bf16 out
// MODE 3: expert last, tile rows, no relu, fp32 scatter to d_out via order[]
template <int MODE>
__global__ __launch_bounds__(256, 2) void gemm128x64(
    const short* __restrict__ A, const short* __restrict__ WT,
    const float* __restrict__ bias, void* __restrict__ Outv,
    const int N, const int K, const long wStride, const int biasN,
    const int* __restrict__ aux, const int* __restrict__ tclass,
    const int* __restrict__ trow0) {

    int tile = blockIdx.y, cls = 0, row0;
    if (MODE <= 1) {
        row0 = tile * BM;
    } else {
        cls = tclass[tile];
        if (cls < 0) return;               // uniform block exit
        row0 = trow0[tile];
    }
    const int n0 = blockIdx.x * BN;
    const short* wt = WT + (size_t)cls * wStride;
    const float* bs = bias + (size_t)cls * biasN;

    __shared__ short As[BM * BK];          // 16 KB
    __shared__ short Bs[BN * BK];          //  8 KB

    const int t = threadIdx.x, lane = t & 63, w = t >> 6;
    const int srow = lane >> 3, scol = (lane & 7) * 8;   // 8 lanes x 16B per row
    const int wr = w >> 1, wc = w & 1;
    const int lrow = lane & 15, lko = lane >> 4;

    v4f acc[4][2] = {};

    for (int k0 = 0; k0 < K; k0 += BK) {
        #pragma unroll
        for (int p = 0; p < 4; ++p) {
            int row = p * 32 + w * 8 + srow;
            gload16(A + (size_t)(row0 + row) * K + k0 + scol, &As[p * 2048 + w * 512]);
        }
        #pragma unroll
        for (int q = 0; q < 2; ++q) {
            int row = q * 32 + w * 8 + srow;
            gload16(wt + (size_t)(n0 + row) * K + k0 + scol, &Bs[q * 2048 + w * 512]);
        }
        __syncthreads();

        #pragma unroll
        for (int kk = 0; kk < 2; ++kk) {
            v8s af[4], bq[2];
            #pragma unroll
            for (int i = 0; i < 4; ++i)
                af[i] = *(const v8s*)&As[(wr * 64 + i * 16 + lrow) * BK + kk * 32 + lko * 8];
            #pragma unroll
            for (int j = 0; j < 2; ++j)
                bq[j] = *(const v8s*)&Bs[(wc * 32 + j * 16 + lrow) * BK + kk * 32 + lko * 8];
            #pragma unroll
            for (int i = 0; i < 4; ++i)
                #pragma unroll
                for (int j = 0; j < 2; ++j)
                    acc[i][j] = __builtin_amdgcn_mfma_f32_16x16x32_bf16(
                        af[i], bq[j], acc[i][j], 0, 0, 0);
        }
        __syncthreads();
    }

    // ---- epilogue ----
    #pragma unroll
    for (int i = 0; i < 4; ++i)
        #pragma unroll
        for (int j = 0; j < 2; ++j)
            #pragma unroll
            for (int q = 0; q < 4; ++q) {
                int r = wr * 64 + i * 16 + lko * 4 + q;   // C/D: row=(l>>4)*4+reg
                int c = wc * 32 + j * 16 + lrow;          //      col=l&15
                if (MODE == 3) {
                    int o = aux[row0 + r];                // order (pos -> sample)
                    if (o >= 0)
                        ((float*)Outv)[(size_t)o * STYLE_D + n0 + c] = acc[i][j][q] + bs[n0 + c];
                } else {
                    float v = fmaxf(acc[i][j][q] + bs[n0 + c], 0.f);
                    size_t orow = (MODE == 1) ? (size_t)aux[row0 + r]   // rank (sample -> pos)
                                              : (size_t)(row0 + r);
                    ((short*)Outv)[orow * N + n0 + c] = f2bf(v);
                }
            }
}

// ---------------- launcher ----------------
extern "C" void kernel_launch(void* const* d_in, const int* in_sizes, int n_in,
                              void* d_out, int out_size, void* d_ws, size_t ws_size,
                              hipStream_t stream) {
    const float* z   = (const float*)d_in[0];
    const int*   y   = (const int*)d_in[1];
    const float* sw0 = (const float*)d_in[2];
    const float* sb0 = (const float*)d_in[3];
    const float* sw1 = (const float*)d_in[4];
    const float* sb1 = (const float*)d_in[5];
    const float* sw2 = (const float*)d_in[6];
    const float* sb2 = (const float*)d_in[7];
    const float* sw3 = (const float*)d_in[8];
    const float* sb3 = (const float*)d_in[9];
    const float* uw0 = (const float*)d_in[10];
    const float* ub0 = (const float*)d_in[11];
    const float* uw1 = (const float*)d_in[12];
    const float* ub1 = (const float*)d_in[13];
    const float* uw2 = (const float*)d_in[14];
    const float* ub2 = (const float*)d_in[15];
    const float* uw3 = (const float*)d_in[16];
    const float* ub3 = (const float*)d_in[17];

    char* p = (char*)d_ws;
    auto alloc = [&](size_t bytes) -> char* {
        char* r = p; p += (bytes + 255) & ~(size_t)255; return r;
    };
    int*   tclass = (int*)alloc(MAXT * 4);
    int*   trow0  = (int*)alloc(MAXT * 4);
    int*   order  = (int*)alloc(MAXROWS * 4);
    int*   rank   = (int*)alloc(B_SAMPLES * 4);
    short* zb     = (short*)alloc((size_t)B_SAMPLES * 64 * 2);
    short* wt0    = (short*)alloc((size_t)HIDDEN * 64 * 2);
    short* wt1    = (short*)alloc((size_t)HIDDEN * HIDDEN * 2);
    short* wt2    = (short*)alloc((size_t)HIDDEN * HIDDEN * 2);
    short* wt3    = (short*)alloc((size_t)HIDDEN * HIDDEN * 2);
    short* wtu0   = (short*)alloc((size_t)NCLS * HIDDEN * HIDDEN * 2);
    short* wtu1   = (short*)alloc((size_t)NCLS * HIDDEN * HIDDEN * 2);
    short* wtu2   = (short*)alloc((size_t)NCLS * HIDDEN * HIDDEN * 2);
    short* wtu3   = (short*)alloc((size_t)NCLS * STYLE_D * HIDDEN * 2);
    short* act0   = (short*)alloc((size_t)MAXROWS * HIDDEN * 2);
    short* act1   = (short*)alloc((size_t)MAXROWS * HIDDEN * 2);
    short* act2   = (short*)alloc((size_t)MAXROWS * HIDDEN * 2);     // sorted trunk out

    // grouping + prep (no memset: pad rows only ever feed pad rows; final
    // scatter drops them via order<0, so garbage there is harmless+deterministic)
    build_groups<<<1, 1024, 0, stream>>>(y, tclass, trow0, order, rank);
    prep_zb_wt0<<<(B_SAMPLES * 64 + HIDDEN * 64) / 256, 256, 0, stream>>>(z, sw0, zb, wt0);
    dim3 tb(32, 8);
    transpose_mega<<<dim3(20, 16, 34), tb, 0, stream>>>(sw1, sw2, sw3, uw0, uw1, uw2, uw3,
                                                        wt1, wt2, wt3, wtu0, wtu1, wtu2, wtu3);

    // trunk
    gemm128x64<0><<<dim3(HIDDEN / BN, B_SAMPLES / BM), 256, 0, stream>>>(
        zb, wt0, sb0, act0, HIDDEN, 64, 0, 0, nullptr, nullptr, nullptr);
    gemm128x64<0><<<dim3(HIDDEN / BN, B_SAMPLES / BM), 256, 0, stream>>>(
        act0, wt1, sb1, act1, HIDDEN, HIDDEN, 0, 0, nullptr, nullptr, nullptr);
    gemm128x64<0><<<dim3(HIDDEN / BN, B_SAMPLES / BM), 256, 0, stream>>>(
        act1, wt2, sb2, act0, HIDDEN, HIDDEN, 0, 0, nullptr, nullptr, nullptr);
    gemm128x64<1><<<dim3(HIDDEN / BN, B_SAMPLES / BM), 256, 0, stream>>>(
        act0, wt3, sb3, act2, HIDDEN, HIDDEN, 0, 0, rank, nullptr, nullptr);

    // selected experts (class-grouped, sorted-linear rows)
    gemm128x64<2><<<dim3(HIDDEN / BN, MAXT), 256, 0, stream>>>(
        act2, wtu0, ub0, act0, HIDDEN, HIDDEN, (long)HIDDEN * HIDDEN, HIDDEN,
        nullptr, tclass, trow0);
    gemm128x64<2><<<dim3(HIDDEN / BN, MAXT), 256, 0, stream>>>(
        act0, wtu1, ub1, act1, HIDDEN, HIDDEN, (long)HIDDEN * HIDDEN, HIDDEN,
        nullptr, tclass, trow0);
    gemm128x64<2><<<dim3(HIDDEN / BN, MAXT), 256, 0, stream>>>(
        act1, wtu2, ub2, act0, HIDDEN, HIDDEN, (long)HIDDEN * HIDDEN, HIDDEN,
        nullptr, tclass, trow0);
    gemm128x64<3><<<dim3(1, MAXT), 256, 0, stream>>>(
        act0, wtu3, ub3, d_out, HIDDEN, HIDDEN, (long)STYLE_D * HIDDEN, STYLE_D,
        order, tclass, trow0);
}